// Round 1
// baseline (153.287 us; speedup 1.0000x reference)
//
#include <hip/hip_runtime.h>

typedef __attribute__((ext_vector_type(8))) short s16x8;
typedef __attribute__((ext_vector_type(4))) float f32x4;

__device__ __forceinline__ short f2bf(float f) {
    union { float f; unsigned u; } c; c.f = f;
    unsigned u = c.u;
    return (short)((u + 0x7fffu + ((u >> 16) & 1u)) >> 16);  // RNE
}

// ---------------------------------------------------------------------------
// K1: precompute
//   blocks 0..511: U[b,:] = x[b]@W1a ; V[b,:] = x[b]@W1b ; 128 elems of W2^T(bf16)
//   block 512:     c0 = q@W1q + g_b1 ; q_exp = relu(relu(q@qe_w1+b1)@qe_w2+b2)
// ---------------------------------------------------------------------------
__global__ __launch_bounds__(256) void rn_k1(
    const float* __restrict__ x, const float* __restrict__ q,
    const float* __restrict__ g_w1, const float* __restrict__ g_b1,
    const float* __restrict__ g_w2,
    const float* __restrict__ qe_w1, const float* __restrict__ qe_b1,
    const float* __restrict__ qe_w2, const float* __restrict__ qe_b2,
    float* __restrict__ U, float* __restrict__ V,
    float* __restrict__ c0, float* __restrict__ qexp,
    short* __restrict__ w2t)
{
    __shared__ float sbuf[64];
    __shared__ float qh[256];
    const int blk = blockIdx.x, t = threadIdx.x;

    if (blk < 512) {
        if (t < 64) sbuf[t] = x[blk * 64 + t];
        __syncthreads();
        float u = 0.f, v = 0.f;
        #pragma unroll 4
        for (int k = 0; k < 64; ++k) {
            float xv = sbuf[k];
            u += xv * g_w1[k * 256 + t];
            v += xv * g_w1[(64 + k) * 256 + t];
        }
        U[blk * 256 + t] = u;
        V[blk * 256 + t] = v;
        if (t < 128) {                      // W2^T bf16: w2t[n*256+k] = g_w2[k*256+n]
            int e = blk * 128 + t;
            int n = e >> 8, k = e & 255;
            w2t[e] = f2bf(g_w2[k * 256 + n]);
        }
    } else {
        if (t < 64) sbuf[t] = q[t];
        __syncthreads();
        float cc = g_b1[t], hh = qe_b1[t];
        #pragma unroll 4
        for (int k = 0; k < 64; ++k) {
            float qv = sbuf[k];
            cc += qv * g_w1[(128 + k) * 256 + t];
            hh += qv * qe_w1[k * 256 + t];
        }
        c0[t] = cc;
        qh[t] = fmaxf(hh, 0.f);
        __syncthreads();
        float qe = qe_b2[t];
        #pragma unroll 4
        for (int k = 0; k < 256; ++k) qe += qh[k] * qe_w2[k * 256 + t];
        qexp[t] = fmaxf(qe, 0.f);
    }
}

// ---------------------------------------------------------------------------
// K2: main. Block beta handles 64 pairs: a = beta>>3, b in [(beta&7)*64, +64).
//   h[i,:] = relu(U[b0+i,:] + V[a,:] + c0)  (bf16, LDS, +8 pad)
//   r = relu(h @ W2 + b2)   via mfma 16x16x32 bf16, 4 waves x 64 cols
//   s_i = r_i . q_exp ; w_i = exp(s_i) (s>=0, bounded -> no max needed)
//   atomicAdd slot: sum(w), sum(w*r) into 64 slots (beta&63)
// ---------------------------------------------------------------------------
__global__ __launch_bounds__(256) void rn_k2(
    const float* __restrict__ U, const float* __restrict__ V,
    const float* __restrict__ c0, const float* __restrict__ qexp,
    const short* __restrict__ w2t, const float* __restrict__ g_b2,
    float* __restrict__ accb)
{
    __shared__ short hT[64][264];          // 256 + 8 pad -> row stride 528 B (16B-aligned, 2-way-only conflicts)
    __shared__ float vc[256];
    __shared__ float srow[4][64];
    __shared__ float wexp_s[64];

    const int beta = blockIdx.x;
    const int a  = beta >> 3;
    const int b0 = (beta & 7) << 6;
    const int tid = threadIdx.x;

    vc[tid] = V[a * 256 + tid] + c0[tid];
    __syncthreads();

    // build h tile: 64 rows x 256 cols
    {
        const int c4 = tid & 63;           // float4 group along cols
        const int r0 = tid >> 6;
        const float4 vcv = *(const float4*)&vc[c4 * 4];
        #pragma unroll
        for (int it = 0; it < 16; ++it) {
            int row = r0 + it * 4;
            float4 uu = *(const float4*)&U[(b0 + row) * 256 + c4 * 4];
            short4 hh;
            hh.x = f2bf(fmaxf(uu.x + vcv.x, 0.f));
            hh.y = f2bf(fmaxf(uu.y + vcv.y, 0.f));
            hh.z = f2bf(fmaxf(uu.z + vcv.z, 0.f));
            hh.w = f2bf(fmaxf(uu.w + vcv.w, 0.f));
            *(short4*)&hT[row][c4 * 4] = hh;
        }
    }
    __syncthreads();

    const int wave = tid >> 6, lane = tid & 63;
    const int l15 = lane & 15, g = lane >> 4;
    const int col0 = wave << 6;

    f32x4 acc[4][4];
    #pragma unroll
    for (int m = 0; m < 4; ++m)
        #pragma unroll
        for (int n = 0; n < 4; ++n)
            acc[m][n] = (f32x4){0.f, 0.f, 0.f, 0.f};

    #pragma unroll
    for (int kk = 0; kk < 8; ++kk) {       // K = 256 in steps of 32
        const int koff = kk * 32 + g * 8;
        s16x8 afr[4], bfr[4];
        #pragma unroll
        for (int m = 0; m < 4; ++m)
            afr[m] = *(const s16x8*)&hT[m * 16 + l15][koff];
        #pragma unroll
        for (int n = 0; n < 4; ++n)
            bfr[n] = *(const s16x8*)&w2t[(col0 + n * 16 + l15) * 256 + koff];
        #pragma unroll
        for (int m = 0; m < 4; ++m)
            #pragma unroll
            for (int n = 0; n < 4; ++n)
                acc[m][n] = __builtin_amdgcn_mfma_f32_16x16x32_bf16(afr[m], bfr[n], acc[m][n], 0, 0, 0);
    }

    // epilogue: bias + relu (in place), scores, exp weights, weighted col sums
    float qe[4], b2c[4];
    #pragma unroll
    for (int n = 0; n < 4; ++n) {
        int col = col0 + n * 16 + l15;
        qe[n]  = qexp[col];
        b2c[n] = g_b2[col];
    }
    #pragma unroll
    for (int m = 0; m < 4; ++m)
        #pragma unroll
        for (int n = 0; n < 4; ++n)
            #pragma unroll
            for (int j = 0; j < 4; ++j)
                acc[m][n][j] = fmaxf(acc[m][n][j] + b2c[n], 0.f);

    // per-row score partials: row = m*16 + g*4 + j, this lane covers cols {col0+n*16+l15}
    #pragma unroll
    for (int m = 0; m < 4; ++m) {
        #pragma unroll
        for (int j = 0; j < 4; ++j) {
            float sp = 0.f;
            #pragma unroll
            for (int n = 0; n < 4; ++n) sp += acc[m][n][j] * qe[n];
            sp += __shfl_xor(sp, 1);
            sp += __shfl_xor(sp, 2);
            sp += __shfl_xor(sp, 4);
            sp += __shfl_xor(sp, 8);       // sum over 16 cols within the 16-lane group
            if (l15 == 0) srow[wave][m * 16 + g * 4 + j] = sp;
        }
    }
    __syncthreads();

    if (tid < 64) {                         // wave 0: full row scores -> exp weights
        float s = srow[0][tid] + srow[1][tid] + srow[2][tid] + srow[3][tid];
        float w = __expf(s);                // s >= 0, bounded; no max subtraction needed
        wexp_s[tid] = w;
        float ls = w;
        ls += __shfl_xor(ls, 1);  ls += __shfl_xor(ls, 2);  ls += __shfl_xor(ls, 4);
        ls += __shfl_xor(ls, 8);  ls += __shfl_xor(ls, 16); ls += __shfl_xor(ls, 32);
        if (tid == 0) atomicAdd(&accb[(beta & 63) * 257 + 256], ls);
    }
    __syncthreads();

    #pragma unroll
    for (int n = 0; n < 4; ++n) {
        float wv = 0.f;
        #pragma unroll
        for (int m = 0; m < 4; ++m)
            #pragma unroll
            for (int j = 0; j < 4; ++j)
                wv += wexp_s[m * 16 + g * 4 + j] * acc[m][n][j];
        wv += __shfl_xor(wv, 16);
        wv += __shfl_xor(wv, 32);           // sum over the 4 row-groups
        if (lane < 16) atomicAdd(&accb[(beta & 63) * 257 + col0 + n * 16 + lane], wv);
    }
}

// ---------------------------------------------------------------------------
// K4: merge 64 slots -> embedding -> f MLP -> out[64]
// ---------------------------------------------------------------------------
__global__ __launch_bounds__(256) void rn_k4(
    const float* __restrict__ accb,
    const float* __restrict__ f_w1, const float* __restrict__ f_b1,
    const float* __restrict__ f_w2, const float* __restrict__ f_b2,
    float* __restrict__ out)
{
    __shared__ float emb[256];
    __shared__ float fh[256];
    const int t = threadIdx.x;

    float v = 0.f, ls = 0.f;
    #pragma unroll 8
    for (int s = 0; s < 64; ++s) {
        v  += accb[s * 257 + t];
        ls += accb[s * 257 + 256];
    }
    emb[t] = v / ls;
    __syncthreads();

    float h = f_b1[t];
    #pragma unroll 4
    for (int k = 0; k < 256; ++k) h += emb[k] * f_w1[k * 256 + t];
    fh[t] = fmaxf(h, 0.f);
    __syncthreads();

    if (t < 64) {
        float o = f_b2[t];
        #pragma unroll 4
        for (int k = 0; k < 256; ++k) o += fh[k] * f_w2[k * 64 + t];
        out[t] = o;
    }
}

extern "C" void kernel_launch(void* const* d_in, const int* in_sizes, int n_in,
                              void* d_out, int out_size, void* d_ws, size_t ws_size,
                              hipStream_t stream) {
    const float* x     = (const float*)d_in[0];
    const float* q     = (const float*)d_in[1];
    const float* g_w1  = (const float*)d_in[2];
    const float* g_b1  = (const float*)d_in[3];
    const float* g_w2  = (const float*)d_in[4];
    const float* g_b2  = (const float*)d_in[5];
    const float* qe_w1 = (const float*)d_in[6];
    const float* qe_b1 = (const float*)d_in[7];
    const float* qe_w2 = (const float*)d_in[8];
    const float* qe_b2 = (const float*)d_in[9];
    const float* f_w1  = (const float*)d_in[10];
    const float* f_b1  = (const float*)d_in[11];
    const float* f_w2  = (const float*)d_in[12];
    const float* f_b2  = (const float*)d_in[13];

    float* wsf  = (float*)d_ws;
    float* U    = wsf;                     // 512*256
    float* V    = wsf + 131072;            // 512*256
    float* c0   = wsf + 262144;            // 256
    float* qexp = wsf + 262400;            // 256
    short* w2t  = (short*)(wsf + 262656);  // 256*256 bf16
    float* accb = wsf + 295424;            // 64 slots * 257 floats

    hipMemsetAsync(accb, 0, 64 * 257 * sizeof(float), stream);

    hipLaunchKernelGGL(rn_k1, dim3(513), dim3(256), 0, stream,
                       x, q, g_w1, g_b1, g_w2, qe_w1, qe_b1, qe_w2, qe_b2,
                       U, V, c0, qexp, w2t);
    hipLaunchKernelGGL(rn_k2, dim3(4096), dim3(256), 0, stream,
                       U, V, c0, qexp, (const short*)w2t, g_b2, accb);
    hipLaunchKernelGGL(rn_k4, dim3(1), dim3(256), 0, stream,
                       accb, f_w1, f_b1, f_w2, f_b2, (float*)d_out);
}

// Round 2
// 102.050 us; speedup vs baseline: 1.5021x; 1.5021x over previous
//
#include <hip/hip_runtime.h>
#include <hip/hip_bf16.h>

typedef __attribute__((ext_vector_type(8))) short s16x8;
typedef __attribute__((ext_vector_type(4))) float f32x4;

__device__ __forceinline__ short f2bf(float f) {
    union { float f; unsigned u; } c; c.f = f;
    unsigned u = c.u;
    return (short)((u + 0x7fffu + ((u >> 16) & 1u)) >> 16);  // RNE
}

// ---------------------------------------------------------------------------
// K1: precompute
//   blocks 0..511: U[b,:]=x[b]@W1a ; V[b,:]=x[b]@W1b ; 256 elems of swizzled W2
//   block 512:     c0 = q@W1q + g_b1 ; q_exp = relu(relu(q@qe_w1+b1)@qe_w2+b2)
// w2s layout: 16B fragment f = (wave*8+kk)*4+n, lane-contiguous:
//   w2s[(f*64+lane)*8 + e] = bf16(g_w2[k*256+col]),
//   col = wave*64+n*16+(lane&15), k = kk*32+(lane>>4)*8+e
// ---------------------------------------------------------------------------
__global__ __launch_bounds__(256) void rn_k1(
    const float* __restrict__ x, const float* __restrict__ q,
    const float* __restrict__ g_w1, const float* __restrict__ g_b1,
    const float* __restrict__ g_w2,
    const float* __restrict__ qe_w1, const float* __restrict__ qe_b1,
    const float* __restrict__ qe_w2, const float* __restrict__ qe_b2,
    float* __restrict__ U, float* __restrict__ V,
    float* __restrict__ c0, float* __restrict__ qexp,
    short* __restrict__ w2s)
{
    __shared__ float sbuf[64];
    __shared__ float qh[256];
    const int blk = blockIdx.x, t = threadIdx.x;

    if (blk < 512) {
        if (t < 64) sbuf[t] = x[blk * 64 + t];
        __syncthreads();
        float u = 0.f, v = 0.f;
        #pragma unroll 4
        for (int k = 0; k < 64; ++k) {
            float xv = sbuf[k];
            u += xv * g_w1[k * 256 + t];
            v += xv * g_w1[(64 + k) * 256 + t];
        }
        U[blk * 256 + t] = u;
        V[blk * 256 + t] = v;
        // swizzled W2 (one bf16 element per thread)
        {
            int E = blk * 256 + t;
            int e = E & 7, f = E >> 3;
            int lane = f & 63, n = (f >> 6) & 3, kk = (f >> 8) & 7, wv = (f >> 11) & 3;
            int l15 = lane & 15, g = lane >> 4;
            int col = wv * 64 + n * 16 + l15;
            int k = kk * 32 + g * 8 + e;
            w2s[E] = f2bf(g_w2[k * 256 + col]);
        }
    } else {
        if (t < 64) sbuf[t] = q[t];
        __syncthreads();
        float cc = g_b1[t], hh = qe_b1[t];
        #pragma unroll 4
        for (int k = 0; k < 64; ++k) {
            float qv = sbuf[k];
            cc += qv * g_w1[(128 + k) * 256 + t];
            hh += qv * qe_w1[k * 256 + t];
        }
        c0[t] = cc;
        qh[t] = fmaxf(hh, 0.f);
        __syncthreads();
        float qe = qe_b2[t];
        #pragma unroll 4
        for (int k = 0; k < 256; ++k) qe += qh[k] * qe_w2[k * 256 + t];
        qexp[t] = fmaxf(qe, 0.f);
    }
}

// ---------------------------------------------------------------------------
// K2: one block per a (512 blocks, 4 waves). W2 held in 128 registers/lane,
// loaded once (coalesced, fragment-order). Loop 8 chunks of 64 b-rows:
//   h = relu(U[b,:] + V[a,:] + c0)  -> LDS bf16
//   r = relu(h @ W2 + b2)           -> mfma 16x16x32, B from registers
//   s = r.qexp ; w = exp(s) ; atomic accumulate sum(w), sum(w*r)
// ---------------------------------------------------------------------------
__global__ __launch_bounds__(256, 2) void rn_k2(
    const float* __restrict__ U, const float* __restrict__ V,
    const float* __restrict__ c0, const float* __restrict__ qexp,
    const short* __restrict__ w2s, const float* __restrict__ g_b2,
    float* __restrict__ accb)
{
    __shared__ short hT[64][264];          // +8 pad: afr row stride 132 dw == 4 mod 32 -> 2-way only
    __shared__ float vc[256];
    __shared__ float srow[4][64];
    __shared__ float wexp_s[64];

    const int a   = blockIdx.x;
    const int tid = threadIdx.x;
    const int wave = tid >> 6, lane = tid & 63;
    const int l15 = lane & 15, g = lane >> 4;
    const int col0 = wave << 6;

    vc[tid] = V[a * 256 + tid] + c0[tid];

    // W2 registers: 32 fragments x 16B, coalesced stream (this wave's 32KB)
    s16x8 w2r[32];
    #pragma unroll
    for (int i = 0; i < 32; ++i)
        w2r[i] = *(const s16x8*)&w2s[((wave * 32 + i) * 64 + lane) * 8];

    float qe[4], b2c[4];
    #pragma unroll
    for (int n = 0; n < 4; ++n) {
        int col = col0 + n * 16 + l15;
        qe[n]  = qexp[col];
        b2c[n] = g_b2[col];
    }

    __syncthreads();                        // vc ready

    const int c4 = tid & 63;
    const int r0 = tid >> 6;
    const float4 vcv = *(const float4*)&vc[c4 * 4];

    for (int cb = 0; cb < 8; ++cb) {
        const int b0 = cb << 6;

        // ---- build h tile: 64 rows x 256 cols (bf16) ----
        #pragma unroll
        for (int it = 0; it < 16; ++it) {
            int row = r0 + it * 4;
            float4 uu = *(const float4*)&U[(b0 + row) * 256 + c4 * 4];
            __hip_bfloat162 p0 = __float22bfloat162_rn(
                make_float2(fmaxf(uu.x + vcv.x, 0.f), fmaxf(uu.y + vcv.y, 0.f)));
            __hip_bfloat162 p1 = __float22bfloat162_rn(
                make_float2(fmaxf(uu.z + vcv.z, 0.f), fmaxf(uu.w + vcv.w, 0.f)));
            uint2 st;
            st.x = *reinterpret_cast<unsigned*>(&p0);
            st.y = *reinterpret_cast<unsigned*>(&p1);
            *reinterpret_cast<uint2*>(&hT[row][c4 * 4]) = st;
        }
        __syncthreads();

        // ---- MFMA: r = h @ W2 (B operand from registers) ----
        f32x4 acc[4][4];
        #pragma unroll
        for (int m = 0; m < 4; ++m)
            #pragma unroll
            for (int n = 0; n < 4; ++n)
                acc[m][n] = (f32x4){0.f, 0.f, 0.f, 0.f};

        #pragma unroll
        for (int kk = 0; kk < 8; ++kk) {
            const int koff = kk * 32 + g * 8;
            s16x8 afr[4];
            #pragma unroll
            for (int m = 0; m < 4; ++m)
                afr[m] = *(const s16x8*)&hT[m * 16 + l15][koff];
            #pragma unroll
            for (int m = 0; m < 4; ++m)
                #pragma unroll
                for (int n = 0; n < 4; ++n)
                    acc[m][n] = __builtin_amdgcn_mfma_f32_16x16x32_bf16(
                        afr[m], w2r[kk * 4 + n], acc[m][n], 0, 0, 0);
        }

        // ---- epilogue: bias+relu, scores, exp weights, weighted sums ----
        #pragma unroll
        for (int m = 0; m < 4; ++m)
            #pragma unroll
            for (int n = 0; n < 4; ++n)
                #pragma unroll
                for (int j = 0; j < 4; ++j)
                    acc[m][n][j] = fmaxf(acc[m][n][j] + b2c[n], 0.f);

        #pragma unroll
        for (int m = 0; m < 4; ++m) {
            #pragma unroll
            for (int j = 0; j < 4; ++j) {
                float sp = 0.f;
                #pragma unroll
                for (int n = 0; n < 4; ++n) sp += acc[m][n][j] * qe[n];
                sp += __shfl_xor(sp, 1);
                sp += __shfl_xor(sp, 2);
                sp += __shfl_xor(sp, 4);
                sp += __shfl_xor(sp, 8);
                if (l15 == 0) srow[wave][m * 16 + g * 4 + j] = sp;
            }
        }
        __syncthreads();

        const int slot = ((a << 3) | cb) & 63;
        if (tid < 64) {
            float s = srow[0][tid] + srow[1][tid] + srow[2][tid] + srow[3][tid];
            float w = __expf(s);            // s >= 0, bounded -> safe
            wexp_s[tid] = w;
            float ls = w;
            ls += __shfl_xor(ls, 1);  ls += __shfl_xor(ls, 2);  ls += __shfl_xor(ls, 4);
            ls += __shfl_xor(ls, 8);  ls += __shfl_xor(ls, 16); ls += __shfl_xor(ls, 32);
            if (tid == 0) atomicAdd(&accb[slot * 257 + 256], ls);
        }
        __syncthreads();

        #pragma unroll
        for (int n = 0; n < 4; ++n) {
            float wv = 0.f;
            #pragma unroll
            for (int m = 0; m < 4; ++m)
                #pragma unroll
                for (int j = 0; j < 4; ++j)
                    wv += wexp_s[m * 16 + g * 4 + j] * acc[m][n][j];
            wv += __shfl_xor(wv, 16);
            wv += __shfl_xor(wv, 32);
            if (lane < 16) atomicAdd(&accb[slot * 257 + col0 + n * 16 + lane], wv);
        }
        // next chunk's hT overwrite is safe: all hT reads happened before the
        // post-srow barrier above.
    }
}

// ---------------------------------------------------------------------------
// K4: merge 64 slots -> embedding -> f MLP -> out[64]
// ---------------------------------------------------------------------------
__global__ __launch_bounds__(256) void rn_k4(
    const float* __restrict__ accb,
    const float* __restrict__ f_w1, const float* __restrict__ f_b1,
    const float* __restrict__ f_w2, const float* __restrict__ f_b2,
    float* __restrict__ out)
{
    __shared__ float emb[256];
    __shared__ float fh[256];
    const int t = threadIdx.x;

    float v = 0.f, ls = 0.f;
    #pragma unroll 8
    for (int s = 0; s < 64; ++s) {
        v  += accb[s * 257 + t];
        ls += accb[s * 257 + 256];
    }
    emb[t] = v / ls;
    __syncthreads();

    float h = f_b1[t];
    #pragma unroll 4
    for (int k = 0; k < 256; ++k) h += emb[k] * f_w1[k * 256 + t];
    fh[t] = fmaxf(h, 0.f);
    __syncthreads();

    if (t < 64) {
        float o = f_b2[t];
        #pragma unroll 4
        for (int k = 0; k < 256; ++k) o += fh[k] * f_w2[k * 64 + t];
        out[t] = o;
    }
}

extern "C" void kernel_launch(void* const* d_in, const int* in_sizes, int n_in,
                              void* d_out, int out_size, void* d_ws, size_t ws_size,
                              hipStream_t stream) {
    const float* x     = (const float*)d_in[0];
    const float* q     = (const float*)d_in[1];
    const float* g_w1  = (const float*)d_in[2];
    const float* g_b1  = (const float*)d_in[3];
    const float* g_w2  = (const float*)d_in[4];
    const float* g_b2  = (const float*)d_in[5];
    const float* qe_w1 = (const float*)d_in[6];
    const float* qe_b1 = (const float*)d_in[7];
    const float* qe_w2 = (const float*)d_in[8];
    const float* qe_b2 = (const float*)d_in[9];
    const float* f_w1  = (const float*)d_in[10];
    const float* f_b1  = (const float*)d_in[11];
    const float* f_w2  = (const float*)d_in[12];
    const float* f_b2  = (const float*)d_in[13];

    float* wsf  = (float*)d_ws;
    float* U    = wsf;                     // 512*256
    float* V    = wsf + 131072;            // 512*256
    float* c0   = wsf + 262144;            // 256
    float* qexp = wsf + 262400;            // 256
    short* w2s  = (short*)(wsf + 262656);  // 256*256 bf16 (swizzled, 131072 shorts)
    float* accb = wsf + 328192;            // 64 slots * 257 floats

    hipMemsetAsync(accb, 0, 64 * 257 * sizeof(float), stream);

    hipLaunchKernelGGL(rn_k1, dim3(513), dim3(256), 0, stream,
                       x, q, g_w1, g_b1, g_w2, qe_w1, qe_b1, qe_w2, qe_b2,
                       U, V, c0, qexp, w2s);
    hipLaunchKernelGGL(rn_k2, dim3(512), dim3(256), 0, stream,
                       U, V, c0, qexp, (const short*)w2s, g_b2, accb);
    hipLaunchKernelGGL(rn_k4, dim3(1), dim3(256), 0, stream,
                       accb, f_w1, f_b1, f_w2, f_b2, (float*)d_out);
}

// Round 3
// 98.267 us; speedup vs baseline: 1.5599x; 1.0385x over previous
//
#include <hip/hip_runtime.h>
#include <hip/hip_bf16.h>

typedef __attribute__((ext_vector_type(8))) short s16x8;
typedef __attribute__((ext_vector_type(4))) float f32x4;

__device__ __forceinline__ short f2bf(float f) {
    union { float f; unsigned u; } c; c.f = f;
    unsigned u = c.u;
    return (short)((u + 0x7fffu + ((u >> 16) & 1u)) >> 16);  // RNE
}

// ---------------------------------------------------------------------------
// K1: precompute
//   blocks 0..511: U[b,:]=x[b]@W1a ; V[b,:]=x[b]@W1b ; 256 elems of swizzled W2
//   block 512:     c0 = q@W1q + g_b1 ; q_exp = relu(relu(q@qe_w1+b1)@qe_w2+b2)
// w2s layout: 16B fragment f = ((wave*8+kk)*4+n), lane-contiguous:
//   w2s[(f*64+lane)*8 + e] = bf16(g_w2[k*256+col]),
//   col = wave*64+n*16+(lane&15), k = kk*32+(lane>>4)*8+e
// ---------------------------------------------------------------------------
__global__ __launch_bounds__(256) void rn_k1(
    const float* __restrict__ x, const float* __restrict__ q,
    const float* __restrict__ g_w1, const float* __restrict__ g_b1,
    const float* __restrict__ g_w2,
    const float* __restrict__ qe_w1, const float* __restrict__ qe_b1,
    const float* __restrict__ qe_w2, const float* __restrict__ qe_b2,
    float* __restrict__ U, float* __restrict__ V,
    float* __restrict__ c0, float* __restrict__ qexp,
    short* __restrict__ w2s)
{
    __shared__ float sbuf[64];
    __shared__ float qh[256];
    const int blk = blockIdx.x, t = threadIdx.x;

    if (blk < 512) {
        if (t < 64) sbuf[t] = x[blk * 64 + t];
        __syncthreads();
        float u = 0.f, v = 0.f;
        #pragma unroll 4
        for (int k = 0; k < 64; ++k) {
            float xv = sbuf[k];
            u += xv * g_w1[k * 256 + t];
            v += xv * g_w1[(64 + k) * 256 + t];
        }
        U[blk * 256 + t] = u;
        V[blk * 256 + t] = v;
        // swizzled W2 (one bf16 element per thread)
        {
            int E = blk * 256 + t;
            int e = E & 7, f = E >> 3;
            int lane = f & 63, n = (f >> 6) & 3, kk = (f >> 8) & 7, wv = (f >> 11) & 3;
            int l15 = lane & 15, g = lane >> 4;
            int col = wv * 64 + n * 16 + l15;
            int k = kk * 32 + g * 8 + e;
            w2s[E] = f2bf(g_w2[k * 256 + col]);
        }
    } else {
        if (t < 64) sbuf[t] = q[t];
        __syncthreads();
        float cc = g_b1[t], hh = qe_b1[t];
        #pragma unroll 4
        for (int k = 0; k < 64; ++k) {
            float qv = sbuf[k];
            cc += qv * g_w1[(128 + k) * 256 + t];
            hh += qv * qe_w1[k * 256 + t];
        }
        c0[t] = cc;
        qh[t] = fmaxf(hh, 0.f);
        __syncthreads();
        float qe = qe_b2[t];
        #pragma unroll 4
        for (int k = 0; k < 256; ++k) qe += qh[k] * qe_w2[k * 256 + t];
        qexp[t] = fmaxf(qe, 0.f);
    }
}

// ---------------------------------------------------------------------------
// K2: one block per (a, 64-row b-chunk): a = bid>>3, b0 = (bid&7)*64.
// 4096 blocks, 4 waves. B fragments streamed per-use from swizzled w2s
// (coalesced, L2-hot). 3 barriers/block. Epilogue: per-wave redundant exp.
// ---------------------------------------------------------------------------
__global__ __launch_bounds__(256, 3) void rn_k2(
    const float* __restrict__ U, const float* __restrict__ V,
    const float* __restrict__ c0, const float* __restrict__ qexp,
    const short* __restrict__ w2s, const float* __restrict__ g_b2,
    float* __restrict__ accb)
{
    __shared__ short hT[64][264];          // +8 pad
    __shared__ float vc[256];
    __shared__ float srow[4][64];

    const int bid = blockIdx.x;
    const int a   = bid >> 3;
    const int b0  = (bid & 7) << 6;
    const int tid = threadIdx.x;
    const int wave = tid >> 6, lane = tid & 63;
    const int l15 = lane & 15, g = lane >> 4;
    const int col0 = wave << 6;

    vc[tid] = V[a * 256 + tid] + c0[tid];

    float qe[4], b2c[4];
    #pragma unroll
    for (int n = 0; n < 4; ++n) {
        int col = col0 + n * 16 + l15;
        qe[n]  = qexp[col];
        b2c[n] = g_b2[col];
    }
    __syncthreads();                        // vc ready

    // ---- build h tile: 64 rows x 256 cols (bf16) ----
    {
        const int c4 = tid & 63;
        const int r0 = tid >> 6;
        const float4 vcv = *(const float4*)&vc[c4 * 4];
        #pragma unroll
        for (int it = 0; it < 16; ++it) {
            int row = r0 + it * 4;
            float4 uu = *(const float4*)&U[(b0 + row) * 256 + c4 * 4];
            __hip_bfloat162 p0 = __float22bfloat162_rn(
                make_float2(fmaxf(uu.x + vcv.x, 0.f), fmaxf(uu.y + vcv.y, 0.f)));
            __hip_bfloat162 p1 = __float22bfloat162_rn(
                make_float2(fmaxf(uu.z + vcv.z, 0.f), fmaxf(uu.w + vcv.w, 0.f)));
            uint2 st;
            st.x = *reinterpret_cast<unsigned*>(&p0);
            st.y = *reinterpret_cast<unsigned*>(&p1);
            *reinterpret_cast<uint2*>(&hT[row][c4 * 4]) = st;
        }
    }
    __syncthreads();                        // hT ready

    // ---- MFMA: r = h @ W2, B streamed from L2 ----
    f32x4 acc[4][4];
    #pragma unroll
    for (int m = 0; m < 4; ++m)
        #pragma unroll
        for (int n = 0; n < 4; ++n)
            acc[m][n] = (f32x4){0.f, 0.f, 0.f, 0.f};

    #pragma unroll
    for (int kk = 0; kk < 8; ++kk) {
        const int koff = kk * 32 + g * 8;
        s16x8 bfr[4];
        #pragma unroll
        for (int n = 0; n < 4; ++n)
            bfr[n] = *(const s16x8*)&w2s[(((wave * 8 + kk) * 4 + n) * 64 + lane) * 8];
        s16x8 afr[4];
        #pragma unroll
        for (int m = 0; m < 4; ++m)
            afr[m] = *(const s16x8*)&hT[m * 16 + l15][koff];
        #pragma unroll
        for (int m = 0; m < 4; ++m)
            #pragma unroll
            for (int n = 0; n < 4; ++n)
                acc[m][n] = __builtin_amdgcn_mfma_f32_16x16x32_bf16(
                    afr[m], bfr[n], acc[m][n], 0, 0, 0);
    }

    // ---- epilogue ----
    #pragma unroll
    for (int m = 0; m < 4; ++m)
        #pragma unroll
        for (int n = 0; n < 4; ++n)
            #pragma unroll
            for (int j = 0; j < 4; ++j)
                acc[m][n][j] = fmaxf(acc[m][n][j] + b2c[n], 0.f);

    // per-wave score partials (this wave's 64 cols) for all 64 rows
    #pragma unroll
    for (int m = 0; m < 4; ++m) {
        #pragma unroll
        for (int j = 0; j < 4; ++j) {
            float sp = 0.f;
            #pragma unroll
            for (int n = 0; n < 4; ++n) sp += acc[m][n][j] * qe[n];
            sp += __shfl_xor(sp, 1);
            sp += __shfl_xor(sp, 2);
            sp += __shfl_xor(sp, 4);
            sp += __shfl_xor(sp, 8);
            if (l15 == 0) srow[wave][m * 16 + g * 4 + j] = sp;
        }
    }
    __syncthreads();                        // srow ready

    // every wave: full row scores -> exp weights (redundant, no broadcast barrier)
    float wrow[4][4];
    #pragma unroll
    for (int m = 0; m < 4; ++m)
        #pragma unroll
        for (int j = 0; j < 4; ++j) {
            int row = m * 16 + g * 4 + j;
            float s = srow[0][row] + srow[1][row] + srow[2][row] + srow[3][row];
            wrow[m][j] = __expf(s);         // s >= 0, bounded -> safe
        }

    const int slot = bid & 63;
    if (wave == 0) {
        float ls = 0.f;
        #pragma unroll
        for (int m = 0; m < 4; ++m)
            #pragma unroll
            for (int j = 0; j < 4; ++j) ls += wrow[m][j];
        ls += __shfl_xor(ls, 16);
        ls += __shfl_xor(ls, 32);           // sum over the 4 row-groups
        if (lane == 0) atomicAdd(&accb[slot * 257 + 256], ls);
    }

    #pragma unroll
    for (int n = 0; n < 4; ++n) {
        float wv = 0.f;
        #pragma unroll
        for (int m = 0; m < 4; ++m)
            #pragma unroll
            for (int j = 0; j < 4; ++j)
                wv += wrow[m][j] * acc[m][n][j];
        wv += __shfl_xor(wv, 16);
        wv += __shfl_xor(wv, 32);
        if (lane < 16) atomicAdd(&accb[slot * 257 + col0 + n * 16 + lane], wv);
    }
}

// ---------------------------------------------------------------------------
// K4: merge 64 slots -> embedding -> f MLP -> out[64]
// ---------------------------------------------------------------------------
__global__ __launch_bounds__(256) void rn_k4(
    const float* __restrict__ accb,
    const float* __restrict__ f_w1, const float* __restrict__ f_b1,
    const float* __restrict__ f_w2, const float* __restrict__ f_b2,
    float* __restrict__ out)
{
    __shared__ float emb[256];
    __shared__ float fh[256];
    const int t = threadIdx.x;

    float v = 0.f, ls = 0.f;
    #pragma unroll 8
    for (int s = 0; s < 64; ++s) {
        v  += accb[s * 257 + t];
        ls += accb[s * 257 + 256];
    }
    emb[t] = v / ls;
    __syncthreads();

    float h = f_b1[t];
    #pragma unroll 4
    for (int k = 0; k < 256; ++k) h += emb[k] * f_w1[k * 256 + t];
    fh[t] = fmaxf(h, 0.f);
    __syncthreads();

    if (t < 64) {
        float o = f_b2[t];
        #pragma unroll 4
        for (int k = 0; k < 256; ++k) o += fh[k] * f_w2[k * 64 + t];
        out[t] = o;
    }
}

extern "C" void kernel_launch(void* const* d_in, const int* in_sizes, int n_in,
                              void* d_out, int out_size, void* d_ws, size_t ws_size,
                              hipStream_t stream) {
    const float* x     = (const float*)d_in[0];
    const float* q     = (const float*)d_in[1];
    const float* g_w1  = (const float*)d_in[2];
    const float* g_b1  = (const float*)d_in[3];
    const float* g_w2  = (const float*)d_in[4];
    const float* g_b2  = (const float*)d_in[5];
    const float* qe_w1 = (const float*)d_in[6];
    const float* qe_b1 = (const float*)d_in[7];
    const float* qe_w2 = (const float*)d_in[8];
    const float* qe_b2 = (const float*)d_in[9];
    const float* f_w1  = (const float*)d_in[10];
    const float* f_b1  = (const float*)d_in[11];
    const float* f_w2  = (const float*)d_in[12];
    const float* f_b2  = (const float*)d_in[13];

    float* wsf  = (float*)d_ws;
    float* U    = wsf;                     // 512*256
    float* V    = wsf + 131072;            // 512*256
    float* c0   = wsf + 262144;            // 256
    float* qexp = wsf + 262400;            // 256
    short* w2s  = (short*)(wsf + 262656);  // 256*256 bf16 (swizzled)
    float* accb = wsf + 328192;            // 64 slots * 257 floats

    hipMemsetAsync(accb, 0, 64 * 257 * sizeof(float), stream);

    hipLaunchKernelGGL(rn_k1, dim3(513), dim3(256), 0, stream,
                       x, q, g_w1, g_b1, g_w2, qe_w1, qe_b1, qe_w2, qe_b2,
                       U, V, c0, qexp, w2s);
    hipLaunchKernelGGL(rn_k2, dim3(4096), dim3(256), 0, stream,
                       U, V, c0, qexp, (const short*)w2s, g_b2, accb);
    hipLaunchKernelGGL(rn_k4, dim3(1), dim3(256), 0, stream,
                       accb, f_w1, f_b1, f_w2, f_b2, (float*)d_out);
}

// Round 4
// 83.058 us; speedup vs baseline: 1.8455x; 1.1831x over previous
//
#include <hip/hip_runtime.h>
#include <hip/hip_bf16.h>

typedef __attribute__((ext_vector_type(8))) short s16x8;
typedef __attribute__((ext_vector_type(4))) float f32x4;

#define NSLOT 128

__device__ __forceinline__ short f2bf(float f) {
    union { float f; unsigned u; } c; c.f = f;
    unsigned u = c.u;
    return (short)((u + 0x7fffu + ((u >> 16) & 1u)) >> 16);  // RNE
}

// ---------------------------------------------------------------------------
// K1: precompute
//   blocks 0..511: U[b,:]=x[b]@W1a ; V[b,:]=x[b]@W1b ; 256 elems of swizzled W2
//   block 512:     c0 = q@W1q + g_b1 ; q_exp = relu(relu(q@qe_w1+b1)@qe_w2+b2)
//   blocks 513+:   zero accb (replaces hipMemsetAsync)
// w2s layout: 16B fragment f = ((wave*8+kk)*4+n), lane-contiguous:
//   w2s[(f*64+lane)*8 + e] = bf16(g_w2[k*256+col]),
//   col = wave*64+n*16+(lane&15), k = kk*32+(lane>>4)*8+e
// ---------------------------------------------------------------------------
__global__ __launch_bounds__(256) void rn_k1(
    const float* __restrict__ x, const float* __restrict__ q,
    const float* __restrict__ g_w1, const float* __restrict__ g_b1,
    const float* __restrict__ g_w2,
    const float* __restrict__ qe_w1, const float* __restrict__ qe_b1,
    const float* __restrict__ qe_w2, const float* __restrict__ qe_b2,
    float* __restrict__ U, float* __restrict__ V,
    float* __restrict__ c0, float* __restrict__ qexp,
    short* __restrict__ w2s, float* __restrict__ accb)
{
    __shared__ float sbuf[64];
    __shared__ float qh[256];
    const int blk = blockIdx.x, t = threadIdx.x;

    if (blk < 512) {
        if (t < 64) sbuf[t] = x[blk * 64 + t];
        __syncthreads();
        float u = 0.f, v = 0.f;
        #pragma unroll 4
        for (int k = 0; k < 64; ++k) {
            float xv = sbuf[k];
            u += xv * g_w1[k * 256 + t];
            v += xv * g_w1[(64 + k) * 256 + t];
        }
        U[blk * 256 + t] = u;
        V[blk * 256 + t] = v;
        // swizzled W2 (one bf16 element per thread)
        {
            int E = blk * 256 + t;
            int e = E & 7, f = E >> 3;
            int lane = f & 63, n = (f >> 6) & 3, kk = (f >> 8) & 7, wv = (f >> 11) & 3;
            int l15 = lane & 15, g = lane >> 4;
            int col = wv * 64 + n * 16 + l15;
            int k = kk * 32 + g * 8 + e;
            w2s[E] = f2bf(g_w2[k * 256 + col]);
        }
    } else if (blk == 512) {
        if (t < 64) sbuf[t] = q[t];
        __syncthreads();
        float cc = g_b1[t], hh = qe_b1[t];
        #pragma unroll 4
        for (int k = 0; k < 64; ++k) {
            float qv = sbuf[k];
            cc += qv * g_w1[(128 + k) * 256 + t];
            hh += qv * qe_w1[k * 256 + t];
        }
        c0[t] = cc;
        qh[t] = fmaxf(hh, 0.f);
        __syncthreads();
        float qe = qe_b2[t];
        #pragma unroll 4
        for (int k = 0; k < 256; ++k) qe += qh[k] * qe_w2[k * 256 + t];
        qexp[t] = fmaxf(qe, 0.f);
    } else {
        // zero accb: NSLOT*257 floats
        const int total = NSLOT * 257;
        int off = (blk - 513) * 2048 + t * 8;
        #pragma unroll
        for (int i = 0; i < 8; ++i)
            if (off + i < total) accb[off + i] = 0.f;
    }
}

// ---------------------------------------------------------------------------
// K2: one block per (a, 64-row b-chunk): a = bid>>3, b0 = (bid&7)*64.
// 4096 blocks, 4 waves, 4 blocks/CU target. B fragments streamed per-use from
// swizzled w2s (coalesced, L2-hot). 2 barriers/block.
// ---------------------------------------------------------------------------
__global__ __launch_bounds__(256, 4) void rn_k2(
    const float* __restrict__ U, const float* __restrict__ V,
    const float* __restrict__ c0, const float* __restrict__ qexp,
    const short* __restrict__ w2s, const float* __restrict__ g_b2,
    float* __restrict__ accb)
{
    __shared__ short hT[64][264];          // 528B pitch: afr b128 reads conflict-free
    __shared__ float srowT[64][4];         // [row][wave]

    const int bid = blockIdx.x;
    const int a   = bid >> 3;
    const int b0  = (bid & 7) << 6;
    const int tid = threadIdx.x;
    const int wave = tid >> 6, lane = tid & 63;
    const int l15 = lane & 15, g = lane >> 4;
    const int col0 = wave << 6;

    // ---- build h tile: 64 rows x 256 cols (bf16), no staging barrier ----
    {
        const int c4 = tid & 63;
        const int r0 = tid >> 6;
        const float4 vv  = *(const float4*)&V[a * 256 + c4 * 4];
        const float4 cc  = *(const float4*)&c0[c4 * 4];
        const float4 vcv = make_float4(vv.x + cc.x, vv.y + cc.y,
                                       vv.z + cc.z, vv.w + cc.w);
        #pragma unroll
        for (int it = 0; it < 16; ++it) {
            int row = r0 + it * 4;
            float4 uu = *(const float4*)&U[(b0 + row) * 256 + c4 * 4];
            __hip_bfloat162 p0 = __float22bfloat162_rn(
                make_float2(fmaxf(uu.x + vcv.x, 0.f), fmaxf(uu.y + vcv.y, 0.f)));
            __hip_bfloat162 p1 = __float22bfloat162_rn(
                make_float2(fmaxf(uu.z + vcv.z, 0.f), fmaxf(uu.w + vcv.w, 0.f)));
            uint2 st;
            st.x = *reinterpret_cast<unsigned*>(&p0);
            st.y = *reinterpret_cast<unsigned*>(&p1);
            *reinterpret_cast<uint2*>(&hT[row][c4 * 4]) = st;
        }
    }

    float qe[4], b2c[4];
    #pragma unroll
    for (int n = 0; n < 4; ++n) {
        int col = col0 + n * 16 + l15;
        qe[n]  = qexp[col];
        b2c[n] = g_b2[col];
    }
    __syncthreads();                        // hT ready

    // ---- MFMA: r = h @ W2, B streamed from L2 ----
    f32x4 acc[4][4];
    #pragma unroll
    for (int m = 0; m < 4; ++m)
        #pragma unroll
        for (int n = 0; n < 4; ++n)
            acc[m][n] = (f32x4){0.f, 0.f, 0.f, 0.f};

    #pragma unroll
    for (int kk = 0; kk < 8; ++kk) {
        const int koff = kk * 32 + g * 8;
        s16x8 bfr[4];
        #pragma unroll
        for (int n = 0; n < 4; ++n)
            bfr[n] = *(const s16x8*)&w2s[(((wave * 8 + kk) * 4 + n) * 64 + lane) * 8];
        s16x8 afr[4];
        #pragma unroll
        for (int m = 0; m < 4; ++m)
            afr[m] = *(const s16x8*)&hT[m * 16 + l15][koff];
        #pragma unroll
        for (int m = 0; m < 4; ++m)
            #pragma unroll
            for (int n = 0; n < 4; ++n)
                acc[m][n] = __builtin_amdgcn_mfma_f32_16x16x32_bf16(
                    afr[m], bfr[n], acc[m][n], 0, 0, 0);
    }

    // ---- epilogue ----
    #pragma unroll
    for (int m = 0; m < 4; ++m)
        #pragma unroll
        for (int n = 0; n < 4; ++n)
            #pragma unroll
            for (int j = 0; j < 4; ++j)
                acc[m][n][j] = fmaxf(acc[m][n][j] + b2c[n], 0.f);

    // per-wave score partials (this wave's 64 cols) for all 64 rows
    #pragma unroll
    for (int m = 0; m < 4; ++m) {
        #pragma unroll
        for (int j = 0; j < 4; ++j) {
            float sp = 0.f;
            #pragma unroll
            for (int n = 0; n < 4; ++n) sp += acc[m][n][j] * qe[n];
            sp += __shfl_xor(sp, 1);
            sp += __shfl_xor(sp, 2);
            sp += __shfl_xor(sp, 4);
            sp += __shfl_xor(sp, 8);
            if (l15 == 0) srowT[m * 16 + g * 4 + j][wave] = sp;
        }
    }
    __syncthreads();                        // srowT ready

    // every wave: full row scores -> exp weights (float4 broadcast reads)
    float wrow[4][4];
    #pragma unroll
    for (int m = 0; m < 4; ++m)
        #pragma unroll
        for (int j = 0; j < 4; ++j) {
            const float4 s4 = *(const float4*)&srowT[m * 16 + g * 4 + j][0];
            wrow[m][j] = __expf(s4.x + s4.y + s4.z + s4.w);  // s >= 0, bounded
        }

    const int slot = bid & (NSLOT - 1);
    if (wave == 0) {
        float ls = 0.f;
        #pragma unroll
        for (int m = 0; m < 4; ++m)
            #pragma unroll
            for (int j = 0; j < 4; ++j) ls += wrow[m][j];
        ls += __shfl_xor(ls, 16);
        ls += __shfl_xor(ls, 32);           // sum over the 4 row-groups
        if (lane == 0) atomicAdd(&accb[slot * 257 + 256], ls);
    }

    #pragma unroll
    for (int n = 0; n < 4; ++n) {
        float wv = 0.f;
        #pragma unroll
        for (int m = 0; m < 4; ++m)
            #pragma unroll
            for (int j = 0; j < 4; ++j)
                wv += wrow[m][j] * acc[m][n][j];
        wv += __shfl_xor(wv, 16);
        wv += __shfl_xor(wv, 32);
        if (lane < 16) atomicAdd(&accb[slot * 257 + col0 + n * 16 + lane], wv);
    }
}

// ---------------------------------------------------------------------------
// K4: merge NSLOT slots -> embedding -> f MLP -> out[64]
// ---------------------------------------------------------------------------
__global__ __launch_bounds__(256) void rn_k4(
    const float* __restrict__ accb,
    const float* __restrict__ f_w1, const float* __restrict__ f_b1,
    const float* __restrict__ f_w2, const float* __restrict__ f_b2,
    float* __restrict__ out)
{
    __shared__ float emb[256];
    __shared__ float fh[256];
    const int t = threadIdx.x;

    float v = 0.f, ls = 0.f;
    #pragma unroll 8
    for (int s = 0; s < NSLOT; ++s) {
        v  += accb[s * 257 + t];
        ls += accb[s * 257 + 256];
    }
    emb[t] = v / ls;
    __syncthreads();

    float h = f_b1[t];
    #pragma unroll 4
    for (int k = 0; k < 256; ++k) h += emb[k] * f_w1[k * 256 + t];
    fh[t] = fmaxf(h, 0.f);
    __syncthreads();

    if (t < 64) {
        float o = f_b2[t];
        #pragma unroll 4
        for (int k = 0; k < 256; ++k) o += fh[k] * f_w2[k * 64 + t];
        out[t] = o;
    }
}

extern "C" void kernel_launch(void* const* d_in, const int* in_sizes, int n_in,
                              void* d_out, int out_size, void* d_ws, size_t ws_size,
                              hipStream_t stream) {
    const float* x     = (const float*)d_in[0];
    const float* q     = (const float*)d_in[1];
    const float* g_w1  = (const float*)d_in[2];
    const float* g_b1  = (const float*)d_in[3];
    const float* g_w2  = (const float*)d_in[4];
    const float* g_b2  = (const float*)d_in[5];
    const float* qe_w1 = (const float*)d_in[6];
    const float* qe_b1 = (const float*)d_in[7];
    const float* qe_w2 = (const float*)d_in[8];
    const float* qe_b2 = (const float*)d_in[9];
    const float* f_w1  = (const float*)d_in[10];
    const float* f_b1  = (const float*)d_in[11];
    const float* f_w2  = (const float*)d_in[12];
    const float* f_b2  = (const float*)d_in[13];

    float* wsf  = (float*)d_ws;
    float* U    = wsf;                     // 512*256
    float* V    = wsf + 131072;            // 512*256
    float* c0   = wsf + 262144;            // 256
    float* qexp = wsf + 262400;            // 256
    short* w2s  = (short*)(wsf + 262656);  // 256*256 bf16 (swizzled)
    float* accb = wsf + 328192;            // NSLOT slots * 257 floats

    // k1 blocks: 512 UV + 1 q + 17 zeroing
    hipLaunchKernelGGL(rn_k1, dim3(530), dim3(256), 0, stream,
                       x, q, g_w1, g_b1, g_w2, qe_w1, qe_b1, qe_w2, qe_b2,
                       U, V, c0, qexp, w2s, accb);
    hipLaunchKernelGGL(rn_k2, dim3(4096), dim3(256), 0, stream,
                       U, V, c0, qexp, (const short*)w2s, g_b2, accb);
    hipLaunchKernelGGL(rn_k4, dim3(1), dim3(256), 0, stream,
                       accb, f_w1, f_b1, f_w2, f_b2, (float*)d_out);
}

// Round 5
// 74.708 us; speedup vs baseline: 2.0518x; 1.1118x over previous
//
#include <hip/hip_runtime.h>
#include <hip/hip_bf16.h>

typedef __attribute__((ext_vector_type(8))) short s16x8;
typedef __attribute__((ext_vector_type(4))) float f32x4;

#define NSLOT 128

__device__ __forceinline__ short f2bf(float f) {
    union { float f; unsigned u; } c; c.f = f;
    unsigned u = c.u;
    return (short)((u + 0x7fffu + ((u >> 16) & 1u)) >> 16);  // RNE
}

// ---------------------------------------------------------------------------
// K1: precompute
//   blocks 0..511: U[b,:]=x[b]@W1a ; V[b,:]=x[b]@W1b ; 256 elems of swizzled W2
//   block 512:     c0 = q@W1q + g_b1 ; q_exp = relu(relu(q@qe_w1+b1)@qe_w2+b2)
//   blocks 513+:   zero accb (replaces hipMemsetAsync)
// w2s layout: 16B fragment f = ((wave*8+kk)*4+n), lane-contiguous:
//   w2s[(f*64+lane)*8 + e] = bf16(g_w2[k*256+col]),
//   col = wave*64+n*16+(lane&15), k = kk*32+(lane>>4)*8+e
// ---------------------------------------------------------------------------
__global__ __launch_bounds__(256) void rn_k1(
    const float* __restrict__ x, const float* __restrict__ q,
    const float* __restrict__ g_w1, const float* __restrict__ g_b1,
    const float* __restrict__ g_w2,
    const float* __restrict__ qe_w1, const float* __restrict__ qe_b1,
    const float* __restrict__ qe_w2, const float* __restrict__ qe_b2,
    float* __restrict__ U, float* __restrict__ V,
    float* __restrict__ c0, float* __restrict__ qexp,
    short* __restrict__ w2s, float* __restrict__ accb)
{
    __shared__ float sbuf[64];
    __shared__ float qh[256];
    const int blk = blockIdx.x, t = threadIdx.x;

    if (blk < 512) {
        if (t < 64) sbuf[t] = x[blk * 64 + t];
        __syncthreads();
        float u = 0.f, v = 0.f;
        #pragma unroll 4
        for (int k = 0; k < 64; ++k) {
            float xv = sbuf[k];
            u += xv * g_w1[k * 256 + t];
            v += xv * g_w1[(64 + k) * 256 + t];
        }
        U[blk * 256 + t] = u;
        V[blk * 256 + t] = v;
        // swizzled W2 (one bf16 element per thread)
        {
            int E = blk * 256 + t;
            int e = E & 7, f = E >> 3;
            int lane = f & 63, n = (f >> 6) & 3, kk = (f >> 8) & 7, wv = (f >> 11) & 3;
            int l15 = lane & 15, g = lane >> 4;
            int col = wv * 64 + n * 16 + l15;
            int k = kk * 32 + g * 8 + e;
            w2s[E] = f2bf(g_w2[k * 256 + col]);
        }
    } else if (blk == 512) {
        if (t < 64) sbuf[t] = q[t];
        __syncthreads();
        float cc = g_b1[t], hh = qe_b1[t];
        #pragma unroll 4
        for (int k = 0; k < 64; ++k) {
            float qv = sbuf[k];
            cc += qv * g_w1[(128 + k) * 256 + t];
            hh += qv * qe_w1[k * 256 + t];
        }
        c0[t] = cc;
        qh[t] = fmaxf(hh, 0.f);
        __syncthreads();
        float qe = qe_b2[t];
        #pragma unroll 4
        for (int k = 0; k < 256; ++k) qe += qh[k] * qe_w2[k * 256 + t];
        qexp[t] = fmaxf(qe, 0.f);
    } else {
        // zero accb: NSLOT*257 floats
        const int total = NSLOT * 257;
        int off = (blk - 513) * 2048 + t * 8;
        #pragma unroll
        for (int i = 0; i < 8; ++i)
            if (off + i < total) accb[off + i] = 0.f;
    }
}

// ---------------------------------------------------------------------------
// K2: one block per (a, 64-row b-chunk). 4096 blocks, 4 waves, 3 blocks/CU.
// Double-buffered B (L2) and A (LDS) fragments: kk+1's loads issued before
// kk's 16-MFMA block, so L2 latency hides under MFMA issue + wave interleave.
// ---------------------------------------------------------------------------
__global__ __launch_bounds__(256, 3) void rn_k2(
    const float* __restrict__ U, const float* __restrict__ V,
    const float* __restrict__ c0, const float* __restrict__ qexp,
    const short* __restrict__ w2s, const float* __restrict__ g_b2,
    float* __restrict__ accb)
{
    __shared__ short hT[64][264];          // 528B pitch: b128 reads conflict-free
    __shared__ float srowT[64][4];         // [row][wave]

    const int bid = blockIdx.x;
    const int a   = bid >> 3;
    const int b0  = (bid & 7) << 6;
    const int tid = threadIdx.x;
    const int wave = tid >> 6, lane = tid & 63;
    const int l15 = lane & 15, g = lane >> 4;
    const int col0 = wave << 6;

    // this wave's swizzled-W2 region; fragment (kk,n) at ((kk*4+n)*64+lane)*8
    const short* w2w = w2s + (wave << 14);
#define BFR_LOAD(kk, n) (*(const s16x8*)&w2w[(((kk) * 4 + (n)) << 9) + (lane << 3)])

    s16x8 bfr[2][4];
    #pragma unroll
    for (int n = 0; n < 4; ++n) bfr[0][n] = BFR_LOAD(0, n);   // pre-barrier issue

    float qe[4], b2c[4];
    #pragma unroll
    for (int n = 0; n < 4; ++n) {
        int col = col0 + n * 16 + l15;
        qe[n]  = qexp[col];
        b2c[n] = g_b2[col];
    }

    // ---- build h tile: 64 rows x 256 cols (bf16) ----
    {
        const int c4 = tid & 63;
        const int r0 = tid >> 6;
        const float4 vv  = *(const float4*)&V[a * 256 + c4 * 4];
        const float4 cc  = *(const float4*)&c0[c4 * 4];
        const float4 vcv = make_float4(vv.x + cc.x, vv.y + cc.y,
                                       vv.z + cc.z, vv.w + cc.w);
        #pragma unroll
        for (int it = 0; it < 16; ++it) {
            int row = r0 + it * 4;
            float4 uu = *(const float4*)&U[(b0 + row) * 256 + c4 * 4];
            __hip_bfloat162 p0 = __float22bfloat162_rn(
                make_float2(fmaxf(uu.x + vcv.x, 0.f), fmaxf(uu.y + vcv.y, 0.f)));
            __hip_bfloat162 p1 = __float22bfloat162_rn(
                make_float2(fmaxf(uu.z + vcv.z, 0.f), fmaxf(uu.w + vcv.w, 0.f)));
            uint2 st;
            st.x = *reinterpret_cast<unsigned*>(&p0);
            st.y = *reinterpret_cast<unsigned*>(&p1);
            *reinterpret_cast<uint2*>(&hT[row][c4 * 4]) = st;
        }
    }
    __syncthreads();                        // hT ready

    // ---- MFMA: r = h @ W2, software-pipelined ----
    f32x4 acc[4][4];
    #pragma unroll
    for (int m = 0; m < 4; ++m)
        #pragma unroll
        for (int n = 0; n < 4; ++n)
            acc[m][n] = (f32x4){0.f, 0.f, 0.f, 0.f};

    s16x8 afr[2][4];
    #pragma unroll
    for (int m = 0; m < 4; ++m)
        afr[0][m] = *(const s16x8*)&hT[m * 16 + l15][g * 8];

    #pragma unroll
    for (int kk = 0; kk < 8; ++kk) {       // fully unrolled: cur/nxt compile-time
        const int cur = kk & 1, nxt = cur ^ 1;
        if (kk < 7) {
            const int koff = (kk + 1) * 32 + g * 8;
            #pragma unroll
            for (int m = 0; m < 4; ++m)
                afr[nxt][m] = *(const s16x8*)&hT[m * 16 + l15][koff];
            #pragma unroll
            for (int n = 0; n < 4; ++n)
                bfr[nxt][n] = BFR_LOAD(kk + 1, n);
        }
        #pragma unroll
        for (int n = 0; n < 4; ++n)
            #pragma unroll
            for (int m = 0; m < 4; ++m)
                acc[m][n] = __builtin_amdgcn_mfma_f32_16x16x32_bf16(
                    afr[cur][m], bfr[cur][n], acc[m][n], 0, 0, 0);
    }
#undef BFR_LOAD

    // ---- epilogue ----
    #pragma unroll
    for (int m = 0; m < 4; ++m)
        #pragma unroll
        for (int n = 0; n < 4; ++n)
            #pragma unroll
            for (int j = 0; j < 4; ++j)
                acc[m][n][j] = fmaxf(acc[m][n][j] + b2c[n], 0.f);

    // per-wave score partials (this wave's 64 cols) for all 64 rows
    #pragma unroll
    for (int m = 0; m < 4; ++m) {
        #pragma unroll
        for (int j = 0; j < 4; ++j) {
            float sp = 0.f;
            #pragma unroll
            for (int n = 0; n < 4; ++n) sp += acc[m][n][j] * qe[n];
            sp += __shfl_xor(sp, 1);
            sp += __shfl_xor(sp, 2);
            sp += __shfl_xor(sp, 4);
            sp += __shfl_xor(sp, 8);
            if (l15 == 0) srowT[m * 16 + g * 4 + j][wave] = sp;
        }
    }
    __syncthreads();                        // srowT ready

    // every wave: full row scores -> exp weights (float4 broadcast reads)
    float wrow[4][4];
    #pragma unroll
    for (int m = 0; m < 4; ++m)
        #pragma unroll
        for (int j = 0; j < 4; ++j) {
            const float4 s4 = *(const float4*)&srowT[m * 16 + g * 4 + j][0];
            wrow[m][j] = __expf(s4.x + s4.y + s4.z + s4.w);  // s >= 0, bounded
        }

    const int slot = bid & (NSLOT - 1);
    if (wave == 0) {
        float ls = 0.f;
        #pragma unroll
        for (int m = 0; m < 4; ++m)
            #pragma unroll
            for (int j = 0; j < 4; ++j) ls += wrow[m][j];
        ls += __shfl_xor(ls, 16);
        ls += __shfl_xor(ls, 32);           // sum over the 4 row-groups
        if (lane == 0) atomicAdd(&accb[slot * 257 + 256], ls);
    }

    #pragma unroll
    for (int n = 0; n < 4; ++n) {
        float wv = 0.f;
        #pragma unroll
        for (int m = 0; m < 4; ++m)
            #pragma unroll
            for (int j = 0; j < 4; ++j)
                wv += wrow[m][j] * acc[m][n][j];
        wv += __shfl_xor(wv, 16);
        wv += __shfl_xor(wv, 32);
        if (lane < 16) atomicAdd(&accb[slot * 257 + col0 + n * 16 + lane], wv);
    }
}

// ---------------------------------------------------------------------------
// K4: merge NSLOT slots -> embedding -> f MLP -> out[64]
// Split accumulators + deep unroll: weight loads pipeline instead of
// serializing on one dependency chain.
// ---------------------------------------------------------------------------
__global__ __launch_bounds__(256) void rn_k4(
    const float* __restrict__ accb,
    const float* __restrict__ f_w1, const float* __restrict__ f_b1,
    const float* __restrict__ f_w2, const float* __restrict__ f_b2,
    float* __restrict__ out)
{
    __shared__ float emb[256];
    __shared__ float fh[256];
    const int t = threadIdx.x;

    float v0 = 0.f, v1 = 0.f, v2 = 0.f, v3 = 0.f;
    float ls = 0.f;
    #pragma unroll
    for (int s = 0; s < NSLOT; s += 4) {
        v0 += accb[(s + 0) * 257 + t];
        v1 += accb[(s + 1) * 257 + t];
        v2 += accb[(s + 2) * 257 + t];
        v3 += accb[(s + 3) * 257 + t];
        ls += accb[s * 257 + 256] + accb[(s + 1) * 257 + 256]
            + accb[(s + 2) * 257 + 256] + accb[(s + 3) * 257 + 256];
    }
    emb[t] = (v0 + v1 + v2 + v3) / ls;
    __syncthreads();

    float h0 = f_b1[t], h1 = 0.f, h2 = 0.f, h3 = 0.f;
    #pragma unroll 8
    for (int k = 0; k < 256; k += 4) {
        h0 += emb[k + 0] * f_w1[(k + 0) * 256 + t];
        h1 += emb[k + 1] * f_w1[(k + 1) * 256 + t];
        h2 += emb[k + 2] * f_w1[(k + 2) * 256 + t];
        h3 += emb[k + 3] * f_w1[(k + 3) * 256 + t];
    }
    fh[t] = fmaxf((h0 + h1) + (h2 + h3), 0.f);
    __syncthreads();

    if (t < 64) {
        float o0 = f_b2[t], o1 = 0.f, o2 = 0.f, o3 = 0.f;
        #pragma unroll 8
        for (int k = 0; k < 256; k += 4) {
            o0 += fh[k + 0] * f_w2[(k + 0) * 64 + t];
            o1 += fh[k + 1] * f_w2[(k + 1) * 64 + t];
            o2 += fh[k + 2] * f_w2[(k + 2) * 64 + t];
            o3 += fh[k + 3] * f_w2[(k + 3) * 64 + t];
        }
        out[t] = (o0 + o1) + (o2 + o3);
    }
}

extern "C" void kernel_launch(void* const* d_in, const int* in_sizes, int n_in,
                              void* d_out, int out_size, void* d_ws, size_t ws_size,
                              hipStream_t stream) {
    const float* x     = (const float*)d_in[0];
    const float* q     = (const float*)d_in[1];
    const float* g_w1  = (const float*)d_in[2];
    const float* g_b1  = (const float*)d_in[3];
    const float* g_w2  = (const float*)d_in[4];
    const float* g_b2  = (const float*)d_in[5];
    const float* qe_w1 = (const float*)d_in[6];
    const float* qe_b1 = (const float*)d_in[7];
    const float* qe_w2 = (const float*)d_in[8];
    const float* qe_b2 = (const float*)d_in[9];
    const float* f_w1  = (const float*)d_in[10];
    const float* f_b1  = (const float*)d_in[11];
    const float* f_w2  = (const float*)d_in[12];
    const float* f_b2  = (const float*)d_in[13];

    float* wsf  = (float*)d_ws;
    float* U    = wsf;                     // 512*256
    float* V    = wsf + 131072;            // 512*256
    float* c0   = wsf + 262144;            // 256
    float* qexp = wsf + 262400;            // 256
    short* w2s  = (short*)(wsf + 262656);  // 256*256 bf16 (swizzled)
    float* accb = wsf + 328192;            // NSLOT slots * 257 floats

    // k1 blocks: 512 UV + 1 q + 17 zeroing
    hipLaunchKernelGGL(rn_k1, dim3(530), dim3(256), 0, stream,
                       x, q, g_w1, g_b1, g_w2, qe_w1, qe_b1, qe_w2, qe_b2,
                       U, V, c0, qexp, w2s, accb);
    hipLaunchKernelGGL(rn_k2, dim3(4096), dim3(256), 0, stream,
                       U, V, c0, qexp, (const short*)w2s, g_b2, accb);
    hipLaunchKernelGGL(rn_k4, dim3(1), dim3(256), 0, stream,
                       accb, f_w1, f_b1, f_w2, f_b2, (float*)d_out);
}

// Round 6
// 72.104 us; speedup vs baseline: 2.1259x; 1.0361x over previous
//
#include <hip/hip_runtime.h>
#include <hip/hip_bf16.h>

typedef __attribute__((ext_vector_type(8))) short s16x8;
typedef __attribute__((ext_vector_type(4))) float f32x4;

#define NSLOT 128

__device__ __forceinline__ short f2bf(float f) {
    union { float f; unsigned u; } c; c.f = f;
    unsigned u = c.u;
    return (short)((u + 0x7fffu + ((u >> 16) & 1u)) >> 16);  // RNE
}
__device__ __forceinline__ float bf2f(short s) {
    union { unsigned u; float f; } c;
    c.u = ((unsigned)(unsigned short)s) << 16;
    return c.f;
}
__device__ __forceinline__ unsigned pk2(float lo, float hi) {
    __hip_bfloat162 p = __float22bfloat162_rn(make_float2(lo, hi));
    return *reinterpret_cast<unsigned*>(&p);
}

// global -> LDS direct DMA, 16B per lane
#define GLD16(gp, lp) __builtin_amdgcn_global_load_lds( \
    (const __attribute__((address_space(1))) unsigned int*)(gp), \
    (__attribute__((address_space(3))) unsigned int*)(lp), 16, 0, 0)

// ---------------------------------------------------------------------------
// K1: precompute
//   blocks 0..511: u8[b, c ^ ((b&7)<<3)] = bf16(x[b]@W1a)   (swizzled bf16 U)
//                  V[b,:] = x[b]@W1b (f32) ; 256 elems of swizzled W2
//   block 512:     c0 = q@W1q + g_b1 ; q_exp = relu(relu(q@qe_w1+b1)@qe_w2+b2)
//   blocks 513+:   zero accb
// w2s layout: 16B fragment f = ((wave*8+kk)*4+n), lane-contiguous.
// ---------------------------------------------------------------------------
__global__ __launch_bounds__(256) void rn_k1(
    const float* __restrict__ x, const float* __restrict__ q,
    const float* __restrict__ g_w1, const float* __restrict__ g_b1,
    const float* __restrict__ g_w2,
    const float* __restrict__ qe_w1, const float* __restrict__ qe_b1,
    const float* __restrict__ qe_w2, const float* __restrict__ qe_b2,
    short* __restrict__ u8, float* __restrict__ V,
    float* __restrict__ c0, float* __restrict__ qexp,
    short* __restrict__ w2s, float* __restrict__ accb)
{
    __shared__ float sbuf[64];
    __shared__ float qh[256];
    const int blk = blockIdx.x, t = threadIdx.x;

    if (blk < 512) {
        if (t < 64) sbuf[t] = x[blk * 64 + t];
        __syncthreads();
        float u = 0.f, v = 0.f;
        #pragma unroll 4
        for (int k = 0; k < 64; ++k) {
            float xv = sbuf[k];
            u += xv * g_w1[k * 256 + t];
            v += xv * g_w1[(64 + k) * 256 + t];
        }
        u8[blk * 256 + (t ^ ((blk & 7) << 3))] = f2bf(u);   // swizzled bf16
        V[blk * 256 + t] = v;
        // swizzled W2 (one bf16 element per thread)
        {
            int E = blk * 256 + t;
            int e = E & 7, f = E >> 3;
            int lane = f & 63, n = (f >> 6) & 3, kk = (f >> 8) & 7, wv = (f >> 11) & 3;
            int l15 = lane & 15, g = lane >> 4;
            int col = wv * 64 + n * 16 + l15;
            int k = kk * 32 + g * 8 + e;
            w2s[E] = f2bf(g_w2[k * 256 + col]);
        }
    } else if (blk == 512) {
        if (t < 64) sbuf[t] = q[t];
        __syncthreads();
        float cc = g_b1[t], hh = qe_b1[t];
        #pragma unroll 4
        for (int k = 0; k < 64; ++k) {
            float qv = sbuf[k];
            cc += qv * g_w1[(128 + k) * 256 + t];
            hh += qv * qe_w1[k * 256 + t];
        }
        c0[t] = cc;
        qh[t] = fmaxf(hh, 0.f);
        __syncthreads();
        float qe = qe_b2[t];
        #pragma unroll 4
        for (int k = 0; k < 256; ++k) qe += qh[k] * qe_w2[k * 256 + t];
        qexp[t] = fmaxf(qe, 0.f);
    } else {
        const int total = NSLOT * 257;
        int off = (blk - 513) * 2048 + t * 8;
        #pragma unroll
        for (int i = 0; i < 8; ++i)
            if (off + i < total) accb[off + i] = 0.f;
    }
}

// ---------------------------------------------------------------------------
// K2: one block per (a, 64-row b-chunk). 4096 blocks, 4 waves, 4 blocks/CU.
// A-tile staged via global_load_lds (bf16, pre-swizzled), h built in place,
// B fragments streamed from L2 (swizzled w2s, compiler-scheduled).
// LDS image: flat [64*256] shorts; element (row,col) at row*256+(col^((row&7)<<3)).
// ---------------------------------------------------------------------------
__global__ __launch_bounds__(256, 4) void rn_k2(
    const float* __restrict__ V, const float* __restrict__ c0,
    const float* __restrict__ qexp, const short* __restrict__ u8,
    const short* __restrict__ w2s, const float* __restrict__ g_b2,
    float* __restrict__ accb)
{
    __shared__ short hT[64 * 256];         // 32KB, XOR-swizzled image
    __shared__ float srowT[64][4];         // [row][wave]

    const int bid = blockIdx.x;
    const int a   = bid >> 3;
    const int b0  = (bid & 7) << 6;
    const int tid = threadIdx.x;
    const int wave = tid >> 6, lane = tid & 63;
    const int l15 = lane & 15, g = lane >> 4;
    const int col0 = wave << 6;

    // ---- stage A-tile: 32 x (64 lanes x 16B) DMA, no VGPR round-trip ----
    {
        const short* src = u8 + b0 * 256;
        #pragma unroll
        for (int i = 0; i < 8; ++i) {
            const int j = wave * 8 + i;
            GLD16(src + j * 512 + lane * 8, hT + j * 512);
        }
    }

    // per-thread build coords (iteration-invariant under the swizzle)
    const int rowb = tid >> 5;                         // 0..7
    const int colb = ((tid & 31) * 8) ^ (rowb << 3);   // unswizzled col base
    float vc8[8];
    {
        const float4 vA = *(const float4*)&V[a * 256 + colb];
        const float4 vB = *(const float4*)&V[a * 256 + colb + 4];
        const float4 cA = *(const float4*)&c0[colb];
        const float4 cB = *(const float4*)&c0[colb + 4];
        vc8[0] = vA.x + cA.x; vc8[1] = vA.y + cA.y;
        vc8[2] = vA.z + cA.z; vc8[3] = vA.w + cA.w;
        vc8[4] = vB.x + cB.x; vc8[5] = vB.y + cB.y;
        vc8[6] = vB.z + cB.z; vc8[7] = vB.w + cB.w;
    }

    float qe[4], b2c[4];
    #pragma unroll
    for (int n = 0; n < 4; ++n) {
        int col = col0 + n * 16 + l15;
        qe[n]  = qexp[col];
        b2c[n] = g_b2[col];
    }

    __syncthreads();                        // stage complete (vmcnt drained)

    // ---- build h in place: h = relu(U + V[a] + c0), bf16 ----
    #pragma unroll
    for (int it = 0; it < 8; ++it) {
        const int si = tid * 8 + it * 2048;
        s16x8 raw = *(const s16x8*)&hT[si];
        float h0 = fmaxf(bf2f(raw[0]) + vc8[0], 0.f);
        float h1 = fmaxf(bf2f(raw[1]) + vc8[1], 0.f);
        float h2 = fmaxf(bf2f(raw[2]) + vc8[2], 0.f);
        float h3 = fmaxf(bf2f(raw[3]) + vc8[3], 0.f);
        float h4 = fmaxf(bf2f(raw[4]) + vc8[4], 0.f);
        float h5 = fmaxf(bf2f(raw[5]) + vc8[5], 0.f);
        float h6 = fmaxf(bf2f(raw[6]) + vc8[6], 0.f);
        float h7 = fmaxf(bf2f(raw[7]) + vc8[7], 0.f);
        uint4 ov;
        ov.x = pk2(h0, h1); ov.y = pk2(h2, h3);
        ov.z = pk2(h4, h5); ov.w = pk2(h6, h7);
        *reinterpret_cast<uint4*>(&hT[si]) = ov;
    }
    __syncthreads();                        // hT ready

    // ---- MFMA: r = h @ W2 ----
    const short* w2w = w2s + (wave << 14);
#define BFR_LOAD(kk, n) (*(const s16x8*)&w2w[(((kk) * 4 + (n)) << 9) + (lane << 3)])
    const int axor  = (l15 & 7) << 3;
    const int arow0 = l15 * 256;

    f32x4 acc[4][4];
    #pragma unroll
    for (int m = 0; m < 4; ++m)
        #pragma unroll
        for (int n = 0; n < 4; ++n)
            acc[m][n] = (f32x4){0.f, 0.f, 0.f, 0.f};

    #pragma unroll
    for (int kk = 0; kk < 8; ++kk) {
        const int koff = kk * 32 + g * 8;
        s16x8 bfr[4];
        #pragma unroll
        for (int n = 0; n < 4; ++n) bfr[n] = BFR_LOAD(kk, n);
        s16x8 afr[4];
        #pragma unroll
        for (int m = 0; m < 4; ++m)
            afr[m] = *(const s16x8*)&hT[arow0 + m * 4096 + (koff ^ axor)];
        __builtin_amdgcn_s_setprio(1);
        #pragma unroll
        for (int m = 0; m < 4; ++m)
            #pragma unroll
            for (int n = 0; n < 4; ++n)
                acc[m][n] = __builtin_amdgcn_mfma_f32_16x16x32_bf16(
                    afr[m], bfr[n], acc[m][n], 0, 0, 0);
        __builtin_amdgcn_s_setprio(0);
    }
#undef BFR_LOAD

    // ---- epilogue ----
    #pragma unroll
    for (int m = 0; m < 4; ++m)
        #pragma unroll
        for (int n = 0; n < 4; ++n)
            #pragma unroll
            for (int j = 0; j < 4; ++j)
                acc[m][n][j] = fmaxf(acc[m][n][j] + b2c[n], 0.f);

    // per-wave score partials (this wave's 64 cols) for all 64 rows
    #pragma unroll
    for (int m = 0; m < 4; ++m) {
        #pragma unroll
        for (int j = 0; j < 4; ++j) {
            float sp = 0.f;
            #pragma unroll
            for (int n = 0; n < 4; ++n) sp += acc[m][n][j] * qe[n];
            sp += __shfl_xor(sp, 1);
            sp += __shfl_xor(sp, 2);
            sp += __shfl_xor(sp, 4);
            sp += __shfl_xor(sp, 8);
            if (l15 == 0) srowT[m * 16 + g * 4 + j][wave] = sp;
        }
    }
    __syncthreads();                        // srowT ready

    // every wave: full row scores -> exp weights (float4 broadcast reads)
    float wrow[4][4];
    #pragma unroll
    for (int m = 0; m < 4; ++m)
        #pragma unroll
        for (int j = 0; j < 4; ++j) {
            const float4 s4 = *(const float4*)&srowT[m * 16 + g * 4 + j][0];
            wrow[m][j] = __expf(s4.x + s4.y + s4.z + s4.w);  // s >= 0, bounded
        }

    const int slot = bid & (NSLOT - 1);
    if (wave == 0) {
        float ls = 0.f;
        #pragma unroll
        for (int m = 0; m < 4; ++m)
            #pragma unroll
            for (int j = 0; j < 4; ++j) ls += wrow[m][j];
        ls += __shfl_xor(ls, 16);
        ls += __shfl_xor(ls, 32);
        if (lane == 0) atomicAdd(&accb[slot * 257 + 256], ls);
    }

    #pragma unroll
    for (int n = 0; n < 4; ++n) {
        float wv = 0.f;
        #pragma unroll
        for (int m = 0; m < 4; ++m)
            #pragma unroll
            for (int j = 0; j < 4; ++j)
                wv += wrow[m][j] * acc[m][n][j];
        wv += __shfl_xor(wv, 16);
        wv += __shfl_xor(wv, 32);
        if (lane < 16) atomicAdd(&accb[slot * 257 + col0 + n * 16 + lane], wv);
    }
}

// ---------------------------------------------------------------------------
// K4: merge NSLOT slots -> embedding -> f MLP -> out[64]
// ---------------------------------------------------------------------------
__global__ __launch_bounds__(256) void rn_k4(
    const float* __restrict__ accb,
    const float* __restrict__ f_w1, const float* __restrict__ f_b1,
    const float* __restrict__ f_w2, const float* __restrict__ f_b2,
    float* __restrict__ out)
{
    __shared__ float emb[256];
    __shared__ float fh[256];
    const int t = threadIdx.x;

    float v0 = 0.f, v1 = 0.f, v2 = 0.f, v3 = 0.f;
    float ls = 0.f;
    #pragma unroll
    for (int s = 0; s < NSLOT; s += 4) {
        v0 += accb[(s + 0) * 257 + t];
        v1 += accb[(s + 1) * 257 + t];
        v2 += accb[(s + 2) * 257 + t];
        v3 += accb[(s + 3) * 257 + t];
        ls += accb[s * 257 + 256] + accb[(s + 1) * 257 + 256]
            + accb[(s + 2) * 257 + 256] + accb[(s + 3) * 257 + 256];
    }
    emb[t] = (v0 + v1 + v2 + v3) / ls;
    __syncthreads();

    float h0 = f_b1[t], h1 = 0.f, h2 = 0.f, h3 = 0.f;
    #pragma unroll 8
    for (int k = 0; k < 256; k += 4) {
        h0 += emb[k + 0] * f_w1[(k + 0) * 256 + t];
        h1 += emb[k + 1] * f_w1[(k + 1) * 256 + t];
        h2 += emb[k + 2] * f_w1[(k + 2) * 256 + t];
        h3 += emb[k + 3] * f_w1[(k + 3) * 256 + t];
    }
    fh[t] = fmaxf((h0 + h1) + (h2 + h3), 0.f);
    __syncthreads();

    if (t < 64) {
        float o0 = f_b2[t], o1 = 0.f, o2 = 0.f, o3 = 0.f;
        #pragma unroll 8
        for (int k = 0; k < 256; k += 4) {
            o0 += fh[k + 0] * f_w2[(k + 0) * 64 + t];
            o1 += fh[k + 1] * f_w2[(k + 1) * 64 + t];
            o2 += fh[k + 2] * f_w2[(k + 2) * 64 + t];
            o3 += fh[k + 3] * f_w2[(k + 3) * 64 + t];
        }
        out[t] = (o0 + o1) + (o2 + o3);
    }
}

extern "C" void kernel_launch(void* const* d_in, const int* in_sizes, int n_in,
                              void* d_out, int out_size, void* d_ws, size_t ws_size,
                              hipStream_t stream) {
    const float* x     = (const float*)d_in[0];
    const float* q     = (const float*)d_in[1];
    const float* g_w1  = (const float*)d_in[2];
    const float* g_b1  = (const float*)d_in[3];
    const float* g_w2  = (const float*)d_in[4];
    const float* g_b2  = (const float*)d_in[5];
    const float* qe_w1 = (const float*)d_in[6];
    const float* qe_b1 = (const float*)d_in[7];
    const float* qe_w2 = (const float*)d_in[8];
    const float* qe_b2 = (const float*)d_in[9];
    const float* f_w1  = (const float*)d_in[10];
    const float* f_b1  = (const float*)d_in[11];
    const float* f_w2  = (const float*)d_in[12];
    const float* f_b2  = (const float*)d_in[13];

    float* wsf  = (float*)d_ws;
    short* u8   = (short*)wsf;             // 512*256 bf16 (swizzled)   [0, 65536)
    float* V    = wsf + 65536;             // 512*256 f32               [65536, 196608)
    float* c0   = wsf + 196608;            // 256
    float* qexp = wsf + 196864;            // 256
    short* w2s  = (short*)(wsf + 197120);  // 256*256 bf16 (swizzled)
    float* accb = wsf + 229888;            // NSLOT slots * 257 floats

    hipLaunchKernelGGL(rn_k1, dim3(530), dim3(256), 0, stream,
                       x, q, g_w1, g_b1, g_w2, qe_w1, qe_b1, qe_w2, qe_b2,
                       u8, V, c0, qexp, w2s, accb);
    hipLaunchKernelGGL(rn_k2, dim3(4096), dim3(256), 0, stream,
                       V, c0, qexp, (const short*)u8, (const short*)w2s, g_b2, accb);
    hipLaunchKernelGGL(rn_k4, dim3(1), dim3(256), 0, stream,
                       accb, f_w1, f_b1, f_w2, f_b2, (float*)d_out);
}